// Round 1
// baseline (286.705 us; speedup 1.0000x reference)
//
#include <hip/hip_runtime.h>
#include <math.h>

#define BG   16
#define NPG  400
#define NN   (BG*NPG)      // 6400 nodes
#define KNN  20
#define NH   8
#define HD   16
#define EM   128
#define NL   3
#define NEGS 0.2f
#define BNEPS 1e-5f
#define MAXDEG 192
#define ROWW 16            // u32 words per adjacency row (512 bits >= 400)

// ---------------- kNN adjacency (bitmask, undirected + self loops) ----------
__global__ __launch_bounds__(256) void knn_kernel(const float* __restrict__ pos,
                                                  unsigned* __restrict__ rowmask) {
    int i = blockIdx.x;                 // global node
    int g = i / NPG, li = i - g * NPG;  // graph, local index
    int t = threadIdx.x;
    __shared__ float d2[NPG];
    __shared__ float rv[256];
    __shared__ int   ri[256];
    const float* pg = pos + (size_t)g * NPG * 2;
    float xi = pg[li * 2], yi = pg[li * 2 + 1];
    for (int j = t; j < NPG; j += 256) {
        float dx = __fsub_rn(xi, pg[j * 2]);
        float dy = __fsub_rn(yi, pg[j * 2 + 1]);
        // exact numpy rounding: dx*dx + dy*dy, no FMA contraction
        d2[j] = __fadd_rn(__fmul_rn(dx, dx), __fmul_rn(dy, dy));
    }
    __syncthreads();
    if (t == 0) {
        d2[li] = INFINITY;  // exclude self from kNN
        atomicOr(&rowmask[(size_t)i * ROWW + (li >> 5)], 1u << (li & 31));  // self loop
    }
    __syncthreads();
    for (int r = 0; r < KNN; ++r) {
        float bv = INFINITY; int bi = NPG;
        for (int j = t; j < NPG; j += 256) {
            float v = d2[j];
            if (v < bv || (v == bv && j < bi)) { bv = v; bi = j; }
        }
        rv[t] = bv; ri[t] = bi;
        __syncthreads();
        for (int s = 128; s > 0; s >>= 1) {
            if (t < s) {
                float ov = rv[t + s]; int oi = ri[t + s];
                if (ov < rv[t] || (ov == rv[t] && oi < ri[t])) { rv[t] = ov; ri[t] = oi; }
            }
            __syncthreads();
        }
        if (t == 0) {
            int j = ri[0];
            d2[j] = INFINITY;
            atomicOr(&rowmask[(size_t)i * ROWW + (j >> 5)], 1u << (j & 31));
            atomicOr(&rowmask[((size_t)g * NPG + j) * ROWW + (li >> 5)], 1u << (li & 31));
        }
        __syncthreads();
    }
}

// ---------------- bitmask -> compact neighbor lists -------------------------
__global__ void nbr_kernel(const unsigned* __restrict__ rowmask,
                           int* __restrict__ nbr, int* __restrict__ cnt) {
    int i = blockIdx.x * blockDim.x + threadIdx.x;
    if (i >= NN) return;
    int base = (i / NPG) * NPG;
    int c = 0;
    for (int w = 0; w < 13; ++w) {
        unsigned m = rowmask[(size_t)i * ROWW + w];
        while (m) {
            int b = __ffs(m) - 1;
            m &= m - 1;
            int j = w * 32 + b;
            if (j < NPG && c < MAXDEG) nbr[(size_t)i * MAXDEG + c++] = base + j;
        }
    }
    cnt[i] = c;
}

// ---------------- input projection ------------------------------------------
__global__ void proj_kernel(const float* __restrict__ x, const float* __restrict__ w,
                            const float* __restrict__ b, float* __restrict__ h) {
    int idx = blockIdx.x * blockDim.x + threadIdx.x;  // n*128 + c
    if (idx >= NN * EM) return;
    int n = idx >> 7, c = idx & 127;
    float acc = x[n * 3 + 0] * w[0 * EM + c] + x[n * 3 + 1] * w[1 * EM + c]
              + x[n * 3 + 2] * w[2 * EM + c] + b[c];
    h[idx] = acc;
}

// ---------------- hh = h @ W (6400x128 @ 128x128) ---------------------------
__global__ __launch_bounds__(256) void matmul_kernel(const float* __restrict__ h,
                                                     const float* __restrict__ w,
                                                     float* __restrict__ out) {
    __shared__ float hs[16][EM];
    int row0 = blockIdx.x * 16;
    int t = threadIdx.x;
    for (int idx = t; idx < 16 * EM; idx += 256)
        hs[idx >> 7][idx & 127] = h[(size_t)row0 * EM + idx];
    __syncthreads();
    int c = t & 127, half = t >> 7;
    float acc[8] = {0, 0, 0, 0, 0, 0, 0, 0};
    for (int k = 0; k < EM; ++k) {
        float wv = w[k * EM + c];
        #pragma unroll
        for (int rr = 0; rr < 8; ++rr) acc[rr] += hs[half * 8 + rr][k] * wv;
    }
    for (int rr = 0; rr < 8; ++rr)
        out[(size_t)(row0 + half * 8 + rr) * EM + c] = acc[rr];
}

// ---------------- per-(node,head) attention scores --------------------------
__global__ void score_kernel(const float* __restrict__ hh, const float* __restrict__ asrc,
                             const float* __restrict__ adst, float* __restrict__ ssrc,
                             float* __restrict__ sdst) {
    int idx = blockIdx.x * blockDim.x + threadIdx.x;  // n*8 + head
    if (idx >= NN * NH) return;
    int n = idx >> 3, hd = idx & 7;
    const float* hp = hh + (size_t)n * EM + hd * HD;
    float s1 = 0.f, s2 = 0.f;
    #pragma unroll
    for (int d = 0; d < HD; ++d) { s1 += hp[d] * asrc[hd * HD + d]; s2 += hp[d] * adst[hd * HD + d]; }
    ssrc[idx] = s1;
    sdst[idx] = s2;
}

// ---------------- sparse masked softmax + aggregate -------------------------
__global__ __launch_bounds__(128) void attn_kernel(const float* __restrict__ hh,
                                                   const int* __restrict__ nbr,
                                                   const int* __restrict__ cnt,
                                                   const float* __restrict__ ssrc,
                                                   const float* __restrict__ sdst,
                                                   const float* __restrict__ bias,
                                                   float* __restrict__ out) {
    int i = blockIdx.x;
    int t = threadIdx.x;  // channel = head*16 + d
    __shared__ float sc[MAXDEG][NH];
    __shared__ int   nb[MAXDEG];
    __shared__ float inv[NH];
    int c = cnt[i];
    for (int j = t; j < c; j += 128) nb[j] = nbr[(size_t)i * MAXDEG + j];
    __syncthreads();
    for (int idx = t; idx < c * NH; idx += 128) {
        int jj = idx >> 3, hd = idx & 7;
        float v = sdst[i * NH + hd] + ssrc[nb[jj] * NH + hd];
        sc[jj][hd] = v >= 0.f ? v : NEGS * v;  // leaky_relu
    }
    __syncthreads();
    if (t < NH) {
        float mx = -INFINITY;
        for (int jj = 0; jj < c; ++jj) mx = fmaxf(mx, sc[jj][t]);
        float s = 0.f;
        for (int jj = 0; jj < c; ++jj) { float e = expf(sc[jj][t] - mx); sc[jj][t] = e; s += e; }
        inv[t] = 1.f / s;
    }
    __syncthreads();
    int hd = t >> 4;
    float acc = 0.f;
    for (int jj = 0; jj < c; ++jj) acc += sc[jj][hd] * hh[(size_t)nb[jj] * EM + t];
    out[(size_t)i * EM + t] = acc * inv[hd] + bias[t];
}

// ---------------- BatchNorm stats (per channel, double accum) ---------------
__global__ __launch_bounds__(256) void bnstat_kernel(const float* __restrict__ x,
                                                     float* __restrict__ mean,
                                                     float* __restrict__ rstd) {
    int c = blockIdx.x;
    int t = threadIdx.x;
    __shared__ double s1[256], s2[256];
    double a = 0.0, b = 0.0;
    for (int n = t; n < NN; n += 256) {
        double v = (double)x[(size_t)n * EM + c];
        a += v; b += v * v;
    }
    s1[t] = a; s2[t] = b;
    __syncthreads();
    for (int s = 128; s > 0; s >>= 1) {
        if (t < s) { s1[t] += s1[t + s]; s2[t] += s2[t + s]; }
        __syncthreads();
    }
    if (t == 0) {
        double m = s1[0] / NN;
        double v = s2[0] / NN - m * m;
        mean[c] = (float)m;
        rstd[c] = rsqrtf((float)v + BNEPS);
    }
}

// ---------------- BN apply + ELU + residual (in-place into h) ---------------
__global__ void bnapply_kernel(const float* __restrict__ gout, const float* __restrict__ mean,
                               const float* __restrict__ rstd, const float* __restrict__ gamma,
                               const float* __restrict__ beta, float* __restrict__ h) {
    int idx = blockIdx.x * blockDim.x + threadIdx.x;
    if (idx >= NN * EM) return;
    int c = idx & 127;
    float v = (gout[idx] - mean[c]) * rstd[c] * gamma[c] + beta[c];
    v = v > 0.f ? v : expm1f(v);  // elu
    h[idx] = v + h[idx];          // residual
}

// ---------------- outputs ----------------------------------------------------
__global__ void copy_kernel(const float* __restrict__ h, float* __restrict__ out) {
    int idx = blockIdx.x * blockDim.x + threadIdx.x;
    if (idx < NN * EM) out[idx] = h[idx];
}

__global__ __launch_bounds__(128) void gmean_kernel(const float* __restrict__ h,
                                                    float* __restrict__ out) {
    int b = blockIdx.x;
    int c = threadIdx.x;  // 128
    float s = 0.f;
    for (int n = 0; n < NPG; ++n) s += h[((size_t)b * NPG + n) * EM + c];
    out[NN * EM + b * EM + c] = s / 400.0f;
}

extern "C" void kernel_launch(void* const* d_in, const int* in_sizes, int n_in,
                              void* d_out, int out_size, void* d_ws, size_t ws_size,
                              hipStream_t stream) {
    const float* x      = (const float*)d_in[0];
    const float* pos    = (const float*)d_in[1];
    // d_in[2] = batch (int32), unused: graphs are contiguous blocks of 400
    const float* proj_w = (const float*)d_in[3];
    const float* proj_b = (const float*)d_in[4];
    const float* lin_w  = (const float*)d_in[5];
    const float* asrc   = (const float*)d_in[6];
    const float* adst   = (const float*)d_in[7];
    const float* gbias  = (const float*)d_in[8];
    const float* gamma  = (const float*)d_in[9];
    const float* beta   = (const float*)d_in[10];
    float* out = (float*)d_out;

    // workspace carve-up (16B aligned chunks)
    char* p = (char*)d_ws;
    auto take = [&](size_t bytes) { char* q = p; p += (bytes + 15) & ~(size_t)15; return q; };
    unsigned* rowmask = (unsigned*)take((size_t)NN * ROWW * 4);
    int*      nbr     = (int*)take((size_t)NN * MAXDEG * 4);
    int*      cnt     = (int*)take((size_t)NN * 4);
    float*    h       = (float*)take((size_t)NN * EM * 4);
    float*    hh      = (float*)take((size_t)NN * EM * 4);
    float*    gout    = (float*)take((size_t)NN * EM * 4);
    float*    ssrc    = (float*)take((size_t)NN * NH * 4);
    float*    sdst    = (float*)take((size_t)NN * NH * 4);
    float*    mean    = (float*)take(EM * 4);
    float*    rstd    = (float*)take(EM * 4);

    hipMemsetAsync(rowmask, 0, (size_t)NN * ROWW * 4, stream);
    knn_kernel<<<NN, 256, 0, stream>>>(pos, rowmask);
    nbr_kernel<<<(NN + 255) / 256, 256, 0, stream>>>(rowmask, nbr, cnt);
    proj_kernel<<<(NN * EM + 255) / 256, 256, 0, stream>>>(x, proj_w, proj_b, h);

    for (int l = 0; l < NL; ++l) {
        matmul_kernel<<<NN / 16, 256, 0, stream>>>(h, lin_w + (size_t)l * EM * EM, hh);
        score_kernel<<<(NN * NH + 255) / 256, 256, 0, stream>>>(hh, asrc + (size_t)l * EM,
                                                                adst + (size_t)l * EM, ssrc, sdst);
        attn_kernel<<<NN, 128, 0, stream>>>(hh, nbr, cnt, ssrc, sdst,
                                            gbias + (size_t)l * EM, gout);
        bnstat_kernel<<<EM, 256, 0, stream>>>(gout, mean, rstd);
        bnapply_kernel<<<(NN * EM + 255) / 256, 256, 0, stream>>>(gout, mean, rstd,
                                                                  gamma + (size_t)l * EM,
                                                                  beta + (size_t)l * EM, h);
    }

    copy_kernel<<<(NN * EM + 255) / 256, 256, 0, stream>>>(h, out);
    gmean_kernel<<<BG, 128, 0, stream>>>(h, out);
}